// Round 9
// baseline (763.154 us; speedup 1.0000x reference)
//
#include <hip/hip_runtime.h>
#include <math.h>

// Problem constants
#define B_    512
#define CIN_  156
#define COUT_ 50
#define T_    325
#define KSR_  100
#define XSZ   (B_*CIN_*T_)           // 25,958,400 (spike_input elems)

// Fixed 4-pass split: per-pass buffers fit the known >=66.6MB workspace.
#define PASSES 4
#define NBP    (B_/PASSES)           // 128 batches per pass

// Workspace byte offsets (fp32 internals, mirroring np float32)
#define EPS_OFF 0                    // 100 floats
#define NU_OFF  512                  // 32 floats
#define PSP_OFF 4096                 // NBP*CIN_*T_ floats = 25,958,400 B
#define U_OFF   (4096 + NBP*CIN_*T_*4)  // NBP*COUT_*T_ floats = 8,320,000 B

// ---------------------------------------------------------------------------
// Setup: alpha kernels EXACTLY as np float32 _alpha_kernel:
//   q = fl32(t/tau); E = fl32(exp(fl32(1 - q))); out = fl32(fl32(mult*q) * E)
// exp computed in fp64 then rounded = correctly-rounded fp32 exp.
// ---------------------------------------------------------------------------
__global__ __launch_bounds__(128) void k_setup(char* __restrict__ ws) {
  float* eps = (float*)(ws + EPS_OFF);
  float* nu  = (float*)(ws + NU_OFF);
  int tid = threadIdx.x;
  if (tid < KSR_) {
    float q   = (float)((double)tid / 10.0);      // CR fp32 divide
    float arg = __fsub_rn(1.0f, q);               // fp32 subtract
    float E   = (float)exp((double)arg);          // CR fp32 exp
    eps[tid]  = __fmul_rn(q, E);                  // mult=1.0: (1*q)*E
  }
  if (tid >= 64 && tid < 96) {
    int s = tid - 64;
    float m   = -20.0f * (float)s;                // exact
    float E   = (float)exp((double)(1 - s));      // CR fp32 exp, int args
    nu[s]     = __fmul_rn(m, E);
  }
}

// ---------------------------------------------------------------------------
// Kernel 1: causal 100-tap conv (psp), fp32, NO fma, s-ASCENDING per-element
// accumulation — mirrors the idiomatic numpy port:
//   psp = zeros; for s in range(100): psp[..., s:] += eps[s]*x[..., :T-s]
// One wave per (bl,c) row; LDS row with 99-zero halo; 6 outputs/lane via
// sliding register window (window slides BACKWARD through LDS as s grows).
// eps[0] = 0 -> s=0 step adds exact zeros, same as the numpy loop.
// ---------------------------------------------------------------------------
__global__ __launch_bounds__(256) void k_conv(const float* __restrict__ x,
                                              const float* __restrict__ eps,
                                              float* __restrict__ psp,
                                              int b0) {
  __shared__ float ly[4][436];
  int wv = threadIdx.x >> 6, lane = threadIdx.x & 63;
  int row = blockIdx.x * 4 + wv;                  // row = bl*CIN_ + c
  const float* xr = x + (size_t)(b0 * CIN_ + row) * T_;
  float* l = ly[wv];
  for (int i = lane; i < 436; i += 64) l[i] = 0.0f;   // halo + tail zeros
  for (int i = lane; i < T_; i += 64) l[99 + i] = xr[i];
  __syncthreads();
  int tb = lane * 6;
  if (tb < T_) {
    float acc[6] = {0, 0, 0, 0, 0, 0};
    float win[6];
    // At step s: win[j] = l[99 + tb + j - s] = x[tb+j-s] (halo zeros if <0)
#pragma unroll
    for (int j = 0; j < 6; ++j) win[j] = l[99 + tb + j];   // s = 0
#pragma unroll
    for (int s = 0; s < KSR_; ++s) {
      float e = eps[s];                               // uniform -> scalarized
#pragma unroll
      for (int j = 0; j < 6; ++j)
        acc[j] = __fadd_rn(acc[j], __fmul_rn(e, win[j]));  // no contraction
      if (s < KSR_ - 1) {
#pragma unroll
        for (int j = 5; j >= 1; --j) win[j] = win[j - 1];  // slide backward
        win[0] = l[98 + tb - s];                      // idx >= tb >= 0
      }
    }
    float* pr = psp + (size_t)row * T_;
#pragma unroll
    for (int j = 0; j < 6; ++j)
      if (tb + j < T_) pr[tb + j] = acc[j];
  }
}

// ---------------------------------------------------------------------------
// Kernel 2: u[bl][o][t] = sum_c (c ASCENDING) w[o][c]*psp[bl][c][t],
// fp32 sequential accumulation, separate mul/add (np.einsum SOP mirror).
// Thread per (bl,t), all 50 o in registers; w reads wave-uniform.
// ---------------------------------------------------------------------------
__global__ __launch_bounds__(256) void k_matmul(const float* __restrict__ psp,
                                                const float* __restrict__ w,
                                                float* __restrict__ u) {
  unsigned tid = blockIdx.x * 256u + threadIdx.x;
  if (tid >= (unsigned)(NBP * T_)) return;
  unsigned bl = tid / (unsigned)T_;
  unsigned t  = tid - bl * (unsigned)T_;
  const float* pp = psp + (size_t)bl * (CIN_ * T_) + t;
  float acc[COUT_];
#pragma unroll
  for (int o = 0; o < COUT_; ++o) acc[o] = 0.0f;
  for (int c = 0; c < CIN_; ++c) {
    float pv = pp[(size_t)c * T_];
#pragma unroll
    for (int o = 0; o < COUT_; ++o)
      acc[o] = __fadd_rn(acc[o], __fmul_rn(w[o * CIN_ + c], pv));
  }
  float* up = u + (size_t)bl * (COUT_ * T_) + t;
#pragma unroll
  for (int o = 0; o < COUT_; ++o) up[(size_t)o * T_] = acc[o];
}

// ---------------------------------------------------------------------------
// Kernel 3: sequential refractory scan, fp32 (all single-rounding ops ->
// bit-matches any fp32 transcription). Thread per (b,o) row.
// v = u + r[0]; s = (v>=10); r[k] = r[k+1] + s*nu[k+1]; r[30] = s*nu[31].
// ---------------------------------------------------------------------------
__global__ __launch_bounds__(64) void k_scan(const float* __restrict__ u,
                                             const float* __restrict__ nu,
                                             float* __restrict__ out,
                                             int row0) {
  int bl = blockIdx.x * 64 + threadIdx.x;           // NBP*COUT_ rows per pass
  const float* up = u + (size_t)bl * T_;
  float* op = out + (size_t)(row0 + bl) * T_;
  float nt[31], r[31];
#pragma unroll
  for (int k = 0; k < 31; ++k) { nt[k] = nu[k + 1]; r[k] = 0.0f; }
#pragma unroll 5
  for (int t = 0; t < T_; ++t) {
    float v = __fadd_rn(up[t], r[0]);
    bool s = (v >= 10.0f);
    float sf = s ? 1.0f : 0.0f;
#pragma unroll
    for (int k = 0; k < 30; ++k)
      r[k] = __fadd_rn(r[k + 1], __fmul_rn(sf, nt[k]));  // s*nu exact
    r[30] = __fmul_rn(sf, nt[30]);
    op[t] = sf;                                     // TS = 1.0
  }
}

// ---------------------------------------------------------------------------
extern "C" void kernel_launch(void* const* d_in, const int* in_sizes, int n_in,
                              void* d_out, int out_size, void* d_ws, size_t ws_size,
                              hipStream_t stream) {
  // Oracle-established dtypes: spike_input fp32, weight fp32, output fp32.
  int xi = (in_sizes[0] == XSZ) ? 0 : 1;
  const float* x = (const float*)d_in[xi];    // [512,156,325] fp32
  const float* w = (const float*)d_in[1 - xi];// [50,156] fp32
  char* ws = (char*)d_ws;
  float* out = (float*)d_out;                 // [512,50,325] fp32 spikes

  const float* eps = (const float*)(ws + EPS_OFF);
  const float* nu  = (const float*)(ws + NU_OFF);
  float* psp       = (float*)(ws + PSP_OFF);
  float* u         = (float*)(ws + U_OFF);

  k_setup<<<1, 128, 0, stream>>>(ws);
  for (int p = 0; p < PASSES; ++p) {
    int b0 = p * NBP;
    int conv_blocks = (NBP * CIN_) / 4;          // 19968/4 = 4992
    int mm_blocks   = (NBP * T_ + 255) / 256;    // 41600 -> 163
    int scan_blocks = (NBP * COUT_) / 64;        // 6400/64 = 100
    k_conv<<<conv_blocks, 256, 0, stream>>>(x, eps, psp, b0);
    k_matmul<<<mm_blocks, 256, 0, stream>>>(psp, w, u);
    k_scan<<<scan_blocks, 64, 0, stream>>>(u, nu, out, b0 * COUT_);
  }
}

// Round 10
// 619.010 us; speedup vs baseline: 1.2329x; 1.2329x over previous
//
#include <hip/hip_runtime.h>
#include <math.h>

// Problem constants
#define B_    512
#define CIN_  156
#define COUT_ 50
#define T_    325
#define KSR_  100
#define XSZ   (B_*CIN_*T_)           // 25,958,400 (spike_input elems)

// 4-pass split over batch for psp; u is FULL-size (fits: 59.3MB < 66.6MB floor)
#define PASSES 4
#define NBP    (B_/PASSES)           // 128 batches per pass
#define OSPLIT 10                    // matmul: o-groups per (bl,t)
#define OG     (COUT_/OSPLIT)        // 5 outputs per thread

// Workspace byte offsets (fp32 internals, mirroring np float32)
#define EPS_OFF 0                    // 100 floats
#define NU_OFF  512                  // 32 floats
#define PSP_OFF 4096                 // NBP*CIN_*T_ floats = 25,958,400 B
#define U_OFF   (PSP_OFF + NBP*CIN_*T_*4)   // FULL u: B_*COUT_*T_*4 = 33,280,000 B

// ---------------------------------------------------------------------------
// Setup: alpha kernels EXACTLY as np float32 _alpha_kernel (unchanged from R9
// — bit-identical tables): q = fl32(t/tau); E = CR-fp32 exp(1-q); q*E.
// ---------------------------------------------------------------------------
__global__ __launch_bounds__(128) void k_setup(char* __restrict__ ws) {
  float* eps = (float*)(ws + EPS_OFF);
  float* nu  = (float*)(ws + NU_OFF);
  int tid = threadIdx.x;
  if (tid < KSR_) {
    float q   = (float)((double)tid / 10.0);
    float arg = __fsub_rn(1.0f, q);
    float E   = (float)exp((double)arg);
    eps[tid]  = __fmul_rn(q, E);
  }
  if (tid >= 64 && tid < 96) {
    int s = tid - 64;
    float m   = -20.0f * (float)s;
    float E   = (float)exp((double)(1 - s));
    nu[s]     = __fmul_rn(m, E);
  }
}

// ---------------------------------------------------------------------------
// Kernel 1: causal 100-tap conv, fp32, NO fma, s-ASCENDING chain per element
// (numerics identical to R9). Scheduling change only: entering window values
// prefetched 10/chunk, double-buffered one chunk ahead -> LDS latency hidden
// behind 120 VALU ops/chunk instead of serialized 1-read-per-step.
// LDS: halo of 103 zeros (s<=99 plus prefetch overreach), data at l[103+i].
// ---------------------------------------------------------------------------
__global__ __launch_bounds__(256) void k_conv(const float* __restrict__ x,
                                              const float* __restrict__ eps,
                                              float* __restrict__ psp,
                                              int b0) {
  __shared__ float ly[4][440];
  int wv = threadIdx.x >> 6, lane = threadIdx.x & 63;
  int row = blockIdx.x * 4 + wv;                  // row = bl*CIN_ + c
  const float* xr = x + (size_t)(b0 * CIN_ + row) * T_;
  float* l = ly[wv];
  for (int i = lane; i < 440; i += 64) l[i] = 0.0f;   // zeros everywhere
  __syncthreads();
  for (int i = lane; i < T_; i += 64) l[103 + i] = xr[i];
  __syncthreads();
  int tb = lane * 6;
  if (tb < T_) {
    float acc[6] = {0, 0, 0, 0, 0, 0};
    float win[6];
#pragma unroll
    for (int j = 0; j < 6; ++j) win[j] = l[103 + tb + j];   // window at s=0
    // Entering value for step s: E(s) = x[tb-s] = l[103+tb-s] (halo zeros).
    float ecur[10], enx[10];
#pragma unroll
    for (int k = 0; k < 10; ++k) ecur[k] = l[103 + tb - k]; // E(0..9); E(0) dummy
#pragma unroll
    for (int chunk = 0; chunk < 10; ++chunk) {
      if (chunk < 9) {
#pragma unroll
        for (int k = 0; k < 10; ++k)
          enx[k] = l[103 + tb - (chunk + 1) * 10 - k];      // min idx = 4+tb
      }
#pragma unroll
      for (int k = 0; k < 10; ++k) {
        int s = chunk * 10 + k;
        if (s > 0) {
#pragma unroll
          for (int j = 5; j >= 1; --j) win[j] = win[j - 1]; // slide (renamed)
          win[0] = ecur[k];
        }
        float e = eps[s];                                   // uniform -> s_load
#pragma unroll
        for (int j = 0; j < 6; ++j)
          acc[j] = __fadd_rn(acc[j], __fmul_rn(e, win[j])); // EXACT R9 chain
      }
#pragma unroll
      for (int k = 0; k < 10; ++k) ecur[k] = enx[k];        // renamed by unroll
    }
    float* pr = psp + (size_t)row * T_;
#pragma unroll
    for (int j = 0; j < 6; ++j)
      if (tb + j < T_) pr[tb + j] = acc[j];
  }
}

// ---------------------------------------------------------------------------
// Kernel 2: u[(b0+bl)][o][t] = sum_c (c ASCENDING, sequential fp32, no fma)
// of w[o][c]*psp[bl][c][t]. Numerics identical; parallelism change only:
// each thread now computes OG=5 outputs (o-group), 10 groups per (bl,t)
// -> 10x wave count (25 waves/CU). og is the slow tid index so w loads stay
// wave-uniform; psp loads stay coalesced along t; u writes coalesced.
// ---------------------------------------------------------------------------
__global__ __launch_bounds__(256) void k_matmul(const float* __restrict__ psp,
                                                const float* __restrict__ w,
                                                float* __restrict__ u,
                                                int b0) {
  unsigned tid = blockIdx.x * 256u + threadIdx.x;   // < OSPLIT*NBP*T_ = 416000
  unsigned og  = tid / (unsigned)(NBP * T_);        // 41600 per group (÷64 ok)
  unsigned rem = tid - og * (unsigned)(NBP * T_);
  unsigned bl  = rem / (unsigned)T_;
  unsigned t   = rem - bl * (unsigned)T_;
  const float* pp = psp + (size_t)bl * (CIN_ * T_) + t;
  const float* wr = w + og * OG * CIN_;
  float acc[OG];
#pragma unroll
  for (int j = 0; j < OG; ++j) acc[j] = 0.0f;
#pragma unroll 4
  for (int c = 0; c < CIN_; ++c) {
    float pv = pp[(size_t)c * T_];
#pragma unroll
    for (int j = 0; j < OG; ++j)
      acc[j] = __fadd_rn(acc[j], __fmul_rn(wr[j * CIN_ + c], pv));
  }
  float* up = u + ((size_t)(b0 + bl) * COUT_ + og * OG) * T_ + t;
#pragma unroll
  for (int j = 0; j < OG; ++j) up[(size_t)j * T_] = acc[j];
}

// ---------------------------------------------------------------------------
// Kernel 3: sequential refractory scan, fp32, ONE dispatch for all 25600 rows
// (was 4 serialized 100-wave dispatches). Body numerics unchanged from R9.
// ---------------------------------------------------------------------------
__global__ __launch_bounds__(64) void k_scan(const float* __restrict__ u,
                                             const float* __restrict__ nu,
                                             float* __restrict__ out) {
  int row = blockIdx.x * 64 + threadIdx.x;          // 400*64 = 25600 exactly
  const float* up = u + (size_t)row * T_;
  float* op = out + (size_t)row * T_;
  float nt[31], r[31];
#pragma unroll
  for (int k = 0; k < 31; ++k) { nt[k] = nu[k + 1]; r[k] = 0.0f; }
#pragma unroll 5
  for (int t = 0; t < T_; ++t) {
    float v = __fadd_rn(up[t], r[0]);
    bool s = (v >= 10.0f);
    float sf = s ? 1.0f : 0.0f;
#pragma unroll
    for (int k = 0; k < 30; ++k)
      r[k] = __fadd_rn(r[k + 1], __fmul_rn(sf, nt[k]));
    r[30] = __fmul_rn(sf, nt[30]);
    op[t] = sf;                                     // TS = 1.0
  }
}

// ---------------------------------------------------------------------------
extern "C" void kernel_launch(void* const* d_in, const int* in_sizes, int n_in,
                              void* d_out, int out_size, void* d_ws, size_t ws_size,
                              hipStream_t stream) {
  int xi = (in_sizes[0] == XSZ) ? 0 : 1;
  const float* x = (const float*)d_in[xi];    // [512,156,325] fp32
  const float* w = (const float*)d_in[1 - xi];// [50,156] fp32
  char* ws = (char*)d_ws;
  float* out = (float*)d_out;                 // [512,50,325] fp32 spikes

  const float* eps = (const float*)(ws + EPS_OFF);
  const float* nu  = (const float*)(ws + NU_OFF);
  float* psp       = (float*)(ws + PSP_OFF);
  float* u         = (float*)(ws + U_OFF);    // full-size u (33.28 MB)

  k_setup<<<1, 128, 0, stream>>>(ws);
  for (int p = 0; p < PASSES; ++p) {
    int b0 = p * NBP;
    k_conv<<<(NBP * CIN_) / 4, 256, 0, stream>>>(x, eps, psp, b0);
    k_matmul<<<(OSPLIT * NBP * T_) / 256, 256, 0, stream>>>(psp, w, u, b0);
  }
  k_scan<<<400, 64, 0, stream>>>(u, nu, out);
}